// Round 1
// baseline (600.135 us; speedup 1.0000x reference)
//
#include <hip/hip_runtime.h>
#include <math.h>

// Problem constants
#define Bsz  4096
#define Tlen 512
#define NE   30
#define NIN  5
#define HD10 10
#define B10  (Bsz*HD10)   // per-head plane: 40960 floats

__device__ __forceinline__ float fexp2(float x){ return __builtin_amdgcn_exp2f(x); }
__device__ __forceinline__ float frcp (float x){ return __builtin_amdgcn_rcpf(x); }
#define L2E 1.4426950408889634f
// sigmoid(x) = 1/(1+e^-x); tanh(x) = 1 - 2/(1+e^{2x}); inf-safe via v_rcp(inf)=0
__device__ __forceinline__ float sigmoid_fast(float x){ return frcp(1.f + fexp2(-L2E*x)); }
__device__ __forceinline__ float tanh_fast(float x){ return 1.f - 2.f*frcp(1.f + fexp2((2.f*L2E)*x)); }

__device__ __forceinline__ void loadarr32(float arr[32], const float* bufrow){
  const float4* p4 = (const float4*)bufrow;
  #pragma unroll
  for (int q4=0;q4<8;q4++){ float4 vv=p4[q4]; arr[4*q4]=vv.x; arr[4*q4+1]=vv.y; arr[4*q4+2]=vv.z; arr[4*q4+3]=vv.w; }
}

// ---------------------------------------------------------------------------
// Kernel 1: fused x-proj + LSTM recurrence + qkv projection.
// One wave per batch element (4096 waves). Lanes: half=lane>>5, j=lane&31.
//   half0,j<30: gates i[j] (acc0) and g[j] (acc1)
//   half1,j<30: gates f[j] (acc0) and o[j] (acc1)
// h kept in per-wave LDS row (32 floats, pads zero); c replicated in lanes j and 32+j.
// Wave-synchronous: no __syncthreads anywhere.
// ---------------------------------------------------------------------------
extern "C" __global__ void __launch_bounds__(256)
lstm_k(const float* __restrict__ input, const float* __restrict__ w_ih,
       const float* __restrict__ w_hh, const float* __restrict__ b_ih,
       const float* __restrict__ b_hh, const float* __restrict__ in_proj_w,
       const float* __restrict__ in_proj_b,
       float* __restrict__ qo, float* __restrict__ ko, float* __restrict__ vo,
       float* __restrict__ ho)
{
  __shared__ __align__(16) float xbuf[4][320];  // 64-step input chunk per wave
  __shared__ __align__(16) float hbuf[4][32];   // h state per wave (pads 30,31 = 0)
  const int wave = threadIdx.x >> 6;
  const int lane = threadIdx.x & 63;
  const int half = lane >> 5;
  const int j    = lane & 31;
  const int b    = blockIdx.x * 4 + wave;
  const bool act = (j < NE);
  const int g0 = half*NE + j;        // i- or f-row
  const int g1 = 60 + half*NE + j;   // g- or o-row

  float wr0[NE], wr1[NE], wi0[NIN], wi1[NIN];
  float bb0 = 0.f, bb1 = 0.f;
  if (act) {
    #pragma unroll
    for (int k2=0;k2<NE;k2++){ wr0[k2]=w_hh[g0*NE+k2]; wr1[k2]=w_hh[g1*NE+k2]; }
    #pragma unroll
    for (int m=0;m<NIN;m++){ wi0[m]=w_ih[g0*NIN+m]; wi1[m]=w_ih[g1*NIN+m]; }
    bb0 = b_ih[g0]+b_hh[g0];
    bb1 = b_ih[g1]+b_hh[g1];
  } else {
    #pragma unroll
    for (int k2=0;k2<NE;k2++){ wr0[k2]=0.f; wr1[k2]=0.f; }
    #pragma unroll
    for (int m=0;m<NIN;m++){ wi0[m]=0.f; wi1[m]=0.f; }
  }
  if (lane < 32) hbuf[wave][lane] = 0.f;   // includes zero pads 30,31
  float c = 0.f;
  // act1: half0 -> tanh via 2*sigmoid(2x)-1 ; half1 -> sigmoid(x)
  const float sIn = half ? 1.f : 2.f;
  const float aMul = half ? 1.f : 2.f;
  const float aAdd = half ? 0.f : -1.f;
  const float* xrow = input + (size_t)b * (Tlen*NIN);
  __builtin_amdgcn_wave_barrier();

  for (int tc = 0; tc < Tlen; tc += 64) {
    // stage 64 steps of input (320 floats) into LDS, coalesced
    #pragma unroll
    for (int r=0;r<5;r++) xbuf[wave][lane + 64*r] = xrow[tc*5 + lane + 64*r];
    __builtin_amdgcn_wave_barrier();
    for (int tl=0; tl<64; ++tl) {
      float hh[32];
      loadarr32(hh, &hbuf[wave][0]);           // broadcast reads
      const float x0 = xbuf[wave][tl*5+0], x1v = xbuf[wave][tl*5+1],
                  x2v = xbuf[wave][tl*5+2], x3v = xbuf[wave][tl*5+3],
                  x4v = xbuf[wave][tl*5+4];
      float a0a = bb0, a0b = 0.f, a1a = bb1, a1b = 0.f;
      a0a = fmaf(wi0[0],x0,a0a);  a1a = fmaf(wi1[0],x0,a1a);
      a0b = fmaf(wi0[1],x1v,a0b); a1b = fmaf(wi1[1],x1v,a1b);
      a0a = fmaf(wi0[2],x2v,a0a); a1a = fmaf(wi1[2],x2v,a1a);
      a0b = fmaf(wi0[3],x3v,a0b); a1b = fmaf(wi1[3],x3v,a1b);
      a0a = fmaf(wi0[4],x4v,a0a); a1a = fmaf(wi1[4],x4v,a1a);
      #pragma unroll
      for (int k2=0;k2<NE;k2+=2){
        a0a = fmaf(wr0[k2],   hh[k2],   a0a);
        a0b = fmaf(wr0[k2+1], hh[k2+1], a0b);
        a1a = fmaf(wr1[k2],   hh[k2],   a1a);
        a1b = fmaf(wr1[k2+1], hh[k2+1], a1b);
      }
      const float ac0 = a0a + a0b;
      const float ac1 = a1a + a1b;
      const float s0 = sigmoid_fast(ac0);               // i (half0) or f (half1)
      const float ss = sigmoid_fast(sIn*ac1);
      const float go = fmaf(aMul, ss, aAdd);            // g (half0) or o (half1)
      const float o0 = __shfl_xor(s0, 32);
      const float o1 = __shfl_xor(go, 32);
      const float iv = half ? o0 : s0;
      const float fv = half ? s0 : o0;
      const float gv = half ? o1 : go;
      const float ov = half ? go : o1;
      c = fmaf(fv, c, iv*gv);
      const float hnew = ov * tanh_fast(c);
      if (half==0 && act) hbuf[wave][j] = hnew;
      __builtin_amdgcn_wave_barrier();
    }
  }

  // ---- tail: q = h@Wq^T+bq (pre-scaled by 1/sqrt(HD)); k,v from c ----
  float* cbuf = &xbuf[wave][0];
  if (half==0) cbuf[lane] = act ? c : 0.f;   // lanes 0..31 (pads 0)
  __builtin_amdgcn_wave_barrier();
  if (half==0 && act) ho[b*NE + j] = hbuf[wave][j];
  const float QS = 0.31622776601683794f;     // 1/sqrt(10)
  #pragma unroll
  for (int rep=0; rep<2; ++rep) {
    const int o = lane + rep*64;
    if (o < 90) {
      const float* wrow = in_proj_w + o*NE;
      const float* src  = (o < NE) ? &hbuf[wave][0] : cbuf;
      float acc = in_proj_b[o];
      #pragma unroll
      for (int k2=0;k2<NE;k2++) acc = fmaf(wrow[k2], src[k2], acc);
      if (o < 30)      { qo[(o/10)*B10 + b*10 + (o%10)] = acc * QS; }
      else if (o < 60) { const int u=o-30; ko[(u/10)*B10 + b*10 + (u%10)] = acc; }
      else             { const int u=o-60; vo[(u/10)*B10 + b*10 + (u%10)] = acc; }
    }
  }
}

// ---------------------------------------------------------------------------
// Kernel 2: flash-style attention over the batch axis. grid=(64 qtiles, 3 heads),
// block=512 (8 waves). Wave w handles key chunks (8 keys each) with chunkIdx%8==w
// for 64 query rows (one per lane); online softmax per thread; LDS merge of the
// 8 partials per query.
// ---------------------------------------------------------------------------
extern "C" __global__ void __launch_bounds__(512)
attn_k(const float* __restrict__ q, const float* __restrict__ k,
       const float* __restrict__ v, float* __restrict__ ctx)
{
  __shared__ float red[8][64][12];
  const int t    = threadIdx.x;
  const int ql   = t & 63;
  const int ks   = t >> 6;
  const int head = blockIdx.y;
  const int qr   = blockIdx.x*64 + ql;
  const float* kh = k + (size_t)head*B10;
  const float* vh = v + (size_t)head*B10;
  float qreg[10];
  {
    const float2* qp = (const float2*)(q + (size_t)head*B10 + qr*10);
    #pragma unroll
    for (int i=0;i<5;i++){ float2 t2=qp[i]; qreg[2*i]=t2.x; qreg[2*i+1]=t2.y; }
  }
  float m = -INFINITY, l = 0.f, acc[10];
  #pragma unroll
  for (int d=0;d<10;d++) acc[d]=0.f;

  for (int ci = ks; ci < Bsz/8; ci += 8) {
    const int k0 = ci*8;
    float s[8];
    #pragma unroll
    for (int u=0;u<8;u++){
      const float2* kp = (const float2*)(kh + (size_t)(k0+u)*10);
      float sv = 0.f;
      #pragma unroll
      for (int i=0;i<5;i++){ float2 kk=kp[i]; sv=fmaf(qreg[2*i],kk.x,sv); sv=fmaf(qreg[2*i+1],kk.y,sv); }
      s[u]=sv;
    }
    float mc = s[0];
    #pragma unroll
    for (int u=1;u<8;u++) mc = fmaxf(mc, s[u]);
    const float mnew = fmaxf(m, mc);
    const float corr = fexp2(L2E*(m - mnew));   // m=-inf first iter -> 0
    l *= corr;
    #pragma unroll
    for (int d=0;d<10;d++) acc[d]*=corr;
    #pragma unroll
    for (int u=0;u<8;u++){
      const float p = fexp2(L2E*(s[u]-mnew));
      l += p;
      const float2* vp = (const float2*)(vh + (size_t)(k0+u)*10);
      #pragma unroll
      for (int i=0;i<5;i++){ float2 vv=vp[i]; acc[2*i]=fmaf(p,vv.x,acc[2*i]); acc[2*i+1]=fmaf(p,vv.y,acc[2*i+1]); }
    }
    m = mnew;
  }
  red[ks][ql][0]=m; red[ks][ql][1]=l;
  #pragma unroll
  for (int d=0;d<10;d++) red[ks][ql][2+d]=acc[d];
  __syncthreads();
  if (t < 64) {
    float M = red[0][t][0];
    #pragma unroll
    for (int i=1;i<8;i++) M = fmaxf(M, red[i][t][0]);
    float L=0.f, o[10];
    #pragma unroll
    for (int d=0;d<10;d++) o[d]=0.f;
    #pragma unroll
    for (int i=0;i<8;i++){
      const float w = fexp2(L2E*(red[i][t][0]-M));
      L = fmaf(red[i][t][1], w, L);
      #pragma unroll
      for (int d=0;d<10;d++) o[d]=fmaf(red[i][t][2+d],w,o[d]);
    }
    const float invL = 1.f/L;
    float* cp = ctx + (size_t)head*B10 + (size_t)(blockIdx.x*64 + t)*10;
    #pragma unroll
    for (int d=0;d<10;d++) cp[d]=o[d]*invL;
  }
}

// ---------------------------------------------------------------------------
// Kernel 3: out_proj + residual + LN + MLP(exact GELU) + LN + head.
// One wave per row; row vector staged in a per-wave 32-float LDS buffer.
// ---------------------------------------------------------------------------
extern "C" __global__ void __launch_bounds__(256)
tail_k(const float* __restrict__ ctx, const float* __restrict__ hn,
       const float* __restrict__ out_proj_w, const float* __restrict__ out_proj_b,
       const float* __restrict__ fc1_w, const float* __restrict__ fc1_b,
       const float* __restrict__ fc2_w, const float* __restrict__ fc2_b,
       const float* __restrict__ ln_g, const float* __restrict__ ln_b,
       const float* __restrict__ out_w, const float* __restrict__ out_b,
       float* __restrict__ out)
{
  __shared__ __align__(16) float buf[4][32];
  const int wave = threadIdx.x >> 6;
  const int lane = threadIdx.x & 63;
  const int b = blockIdx.x*4 + wave;
  const bool act = (lane < NE);
  if (lane < 32) buf[wave][lane] = 0.f;
  __builtin_amdgcn_wave_barrier();
  if (act) buf[wave][lane] = ctx[(lane/10)*B10 + b*10 + (lane%10)];
  __builtin_amdgcn_wave_barrier();
  float arr[32];
  loadarr32(arr, &buf[wave][0]);
  const float hv = act ? hn[b*NE+lane] : 0.f;
  float x = 0.f;
  if (act) {
    float a = out_proj_b[lane];
    #pragma unroll
    for (int k2=0;k2<NE;k2++) a = fmaf(out_proj_w[lane*NE+k2], arr[k2], a);
    x = a + hv;                       // attn_out + h_n
  }
  // LN1
  __builtin_amdgcn_wave_barrier();
  if (act) buf[wave][lane] = x;
  __builtin_amdgcn_wave_barrier();
  loadarr32(arr, &buf[wave][0]);
  float s1=0.f, s2=0.f;
  #pragma unroll
  for (int k2=0;k2<32;k2++){ s1+=arr[k2]; s2=fmaf(arr[k2],arr[k2],s2); }
  float mu = s1*(1.f/30.f);
  float var = s2*(1.f/30.f) - mu*mu;
  float rs = rsqrtf(var + 1e-5f);
  float x1 = 0.f;
  if (act) x1 = fmaf((x-mu)*rs, ln_g[lane], ln_b[lane]);
  // fc1 + exact GELU
  __builtin_amdgcn_wave_barrier();
  if (act) buf[wave][lane] = x1;
  __builtin_amdgcn_wave_barrier();
  loadarr32(arr, &buf[wave][0]);
  float gv = 0.f;
  if (act) {
    float a = fc1_b[lane];
    #pragma unroll
    for (int k2=0;k2<NE;k2++) a = fmaf(fc1_w[lane*NE+k2], arr[k2], a);
    gv = 0.5f*a*(1.f + erff(a*0.70710678118654752f));
  }
  // fc2
  __builtin_amdgcn_wave_barrier();
  if (act) buf[wave][lane] = gv;
  __builtin_amdgcn_wave_barrier();
  loadarr32(arr, &buf[wave][0]);
  float y = 0.f;
  if (act) {
    float a = fc2_b[lane];
    #pragma unroll
    for (int k2=0;k2<NE;k2++) a = fmaf(fc2_w[lane*NE+k2], arr[k2], a);
    y = x1 + a;                        // residual x1 + fc
  }
  // LN2
  __builtin_amdgcn_wave_barrier();
  if (act) buf[wave][lane] = y;
  __builtin_amdgcn_wave_barrier();
  loadarr32(arr, &buf[wave][0]);
  s1=0.f; s2=0.f;
  #pragma unroll
  for (int k2=0;k2<32;k2++){ s1+=arr[k2]; s2=fmaf(arr[k2],arr[k2],s2); }
  mu = s1*(1.f/30.f);
  var = s2*(1.f/30.f) - mu*mu;
  rs = rsqrtf(var + 1e-5f);
  float x2 = 0.f;
  if (act) x2 = fmaf((y-mu)*rs, ln_g[lane], ln_b[lane]);
  // head: [3,30]
  __builtin_amdgcn_wave_barrier();
  if (act) buf[wave][lane] = x2;
  __builtin_amdgcn_wave_barrier();
  loadarr32(arr, &buf[wave][0]);
  if (lane < 3) {
    float a = out_b[lane];
    #pragma unroll
    for (int k2=0;k2<NE;k2++) a = fmaf(out_w[lane*NE+k2], arr[k2], a);
    out[b*3 + lane] = a;
  }
}

extern "C" void kernel_launch(void* const* d_in, const int* in_sizes, int n_in,
                              void* d_out, int out_size, void* d_ws, size_t ws_size,
                              hipStream_t stream)
{
  const float* input      = (const float*)d_in[0];
  const float* w_ih       = (const float*)d_in[1];
  const float* w_hh       = (const float*)d_in[2];
  const float* b_ih       = (const float*)d_in[3];
  const float* b_hh       = (const float*)d_in[4];
  const float* in_proj_w  = (const float*)d_in[5];
  const float* in_proj_b  = (const float*)d_in[6];
  const float* out_proj_w = (const float*)d_in[7];
  const float* out_proj_b = (const float*)d_in[8];
  const float* fc1_w      = (const float*)d_in[9];
  const float* fc1_b      = (const float*)d_in[10];
  const float* fc2_w      = (const float*)d_in[11];
  const float* fc2_b      = (const float*)d_in[12];
  const float* ln_g       = (const float*)d_in[13];
  const float* ln_b       = (const float*)d_in[14];
  const float* out_w      = (const float*)d_in[15];
  const float* out_b      = (const float*)d_in[16];

  float* ws = (float*)d_ws;
  float* qo = ws;                 // [3][4096][10]
  float* ko = ws + 122880;        // [3][4096][10]
  float* vo = ws + 245760;        // [3][4096][10]
  float* hn = ws + 368640;        // [4096][30]
  float* cx = ws + 491520;        // [3][4096][10]

  lstm_k<<<Bsz/4, 256, 0, stream>>>(input, w_ih, w_hh, b_ih, b_hh,
                                    in_proj_w, in_proj_b, qo, ko, vo, hn);
  attn_k<<<dim3(Bsz/64, 3), 512, 0, stream>>>(qo, ko, vo, cx);
  tail_k<<<Bsz/4, 256, 0, stream>>>(cx, hn, out_proj_w, out_proj_b,
                                    fc1_w, fc1_b, fc2_w, fc2_b,
                                    ln_g, ln_b, out_w, out_b, (float*)d_out);
}

// Round 2
// 518.498 us; speedup vs baseline: 1.1574x; 1.1574x over previous
//
#include <hip/hip_runtime.h>
#include <math.h>

// Problem constants
#define Bsz  4096
#define Tlen 512
#define NE   30
#define NIN  5
#define HD10 10
#define B10  (Bsz*HD10)   // per-head plane: 40960 floats

typedef _Float16 h2v __attribute__((ext_vector_type(2)));

__device__ __forceinline__ float fexp2(float x){ return __builtin_amdgcn_exp2f(x); }
__device__ __forceinline__ float frcp (float x){ return __builtin_amdgcn_rcpf(x); }
#define L2E 1.4426950408889634f
__device__ __forceinline__ float sigmoid_fast(float x){ return frcp(1.f + fexp2(-L2E*x)); }
__device__ __forceinline__ float tanh_fast(float x){ return 1.f - 2.f*frcp(1.f + fexp2((2.f*L2E)*x)); }

#if __has_builtin(__builtin_amdgcn_fdot2)
__device__ __forceinline__ float fdot2(h2v a, h2v b, float c){
  return __builtin_amdgcn_fdot2(a, b, c, false);
}
#else
__device__ __forceinline__ float fdot2(h2v a, h2v b, float c){
  return fmaf((float)a.x, (float)b.x, fmaf((float)a.y, (float)b.y, c));
}
#endif

__device__ __forceinline__ h2v bch2(float x){ return __builtin_bit_cast(h2v, x); }

__device__ __forceinline__ void loadarr32(float arr[32], const float* bufrow){
  const float4* p4 = (const float4*)bufrow;
  #pragma unroll
  for (int q4=0;q4<8;q4++){ float4 vv=p4[q4]; arr[4*q4]=vv.x; arr[4*q4+1]=vv.y; arr[4*q4+2]=vv.z; arr[4*q4+3]=vv.w; }
}

// ---------------------------------------------------------------------------
// Kernel 1: fused x-proj + LSTM recurrence + qkv projection.
// One wave per batch element. Lanes: half=lane>>5, j=lane&31.
//   half0,j<30: gates i[j] (acc0) and g[j] (acc1)
//   half1,j<30: gates f[j] (acc0) and o[j] (acc1)
// h state packed fp16 (half2 pairs) in LDS; recurrence matvec via v_dot2_f32_f16
// (fp32 accumulate). Input projection stays fp32. Wave-synchronous.
// ---------------------------------------------------------------------------
extern "C" __global__ void __launch_bounds__(256, 4)
lstm_k(const float* __restrict__ input, const float* __restrict__ w_ih,
       const float* __restrict__ w_hh, const float* __restrict__ b_ih,
       const float* __restrict__ b_hh, const float* __restrict__ in_proj_w,
       const float* __restrict__ in_proj_b,
       float* __restrict__ qo, float* __restrict__ ko, float* __restrict__ vo,
       float* __restrict__ ho)
{
  __shared__ __align__(16) float xbuf[4][320];  // 64-step input chunk per wave
  __shared__ __align__(16) float hp[4][16];     // h as 16 packed half2 (pair 15 = 0)
  const int wave = threadIdx.x >> 6;
  const int lane = threadIdx.x & 63;
  const int half = lane >> 5;
  const int j    = lane & 31;
  const int b    = blockIdx.x * 4 + wave;
  const bool act = (j < NE);
  const int g0 = half*NE + j;        // i- or f-row
  const int g1 = 60 + half*NE + j;   // g- or o-row

  // packed fp16 weight pairs (index 15 = zero pad)
  h2v wr0p[16], wr1p[16];
  float wi0[NIN], wi1[NIN];
  float bb0 = 0.f, bb1 = 0.f;
  #pragma unroll
  for (int k2=0;k2<16;k2++){ wr0p[k2]=(h2v)0; wr1p[k2]=(h2v)0; }
  #pragma unroll
  for (int m=0;m<NIN;m++){ wi0[m]=0.f; wi1[m]=0.f; }
  if (act) {
    #pragma unroll
    for (int k2=0;k2<15;k2++){
      h2v w0, w1;
      w0.x = (_Float16)w_hh[g0*NE+2*k2];   w0.y = (_Float16)w_hh[g0*NE+2*k2+1];
      w1.x = (_Float16)w_hh[g1*NE+2*k2];   w1.y = (_Float16)w_hh[g1*NE+2*k2+1];
      wr0p[k2]=w0; wr1p[k2]=w1;
    }
    #pragma unroll
    for (int m=0;m<NIN;m++){ wi0[m]=w_ih[g0*NIN+m]; wi1[m]=w_ih[g1*NIN+m]; }
    bb0 = b_ih[g0]+b_hh[g0];
    bb1 = b_ih[g1]+b_hh[g1];
  }
  if (lane < 16) hp[wave][lane] = 0.f;   // zero-packed h (incl pad pair 15)
  float c = 0.f, hlast = 0.f;
  // half0 -> tanh via 2*sigmoid(2x)-1 ; half1 -> sigmoid(x)
  const float sIn  = half ? 1.f : 2.f;
  const float aMul = half ? 1.f : 2.f;
  const float aAdd = half ? 0.f : -1.f;
  const float* xrow = input + (size_t)b * (Tlen*NIN);
  __builtin_amdgcn_wave_barrier();

  for (int tc = 0; tc < Tlen; tc += 64) {
    // stage 64 steps of input (320 floats) into LDS, coalesced
    #pragma unroll
    for (int r=0;r<5;r++) xbuf[wave][lane + 64*r] = xrow[tc*5 + lane + 64*r];
    __builtin_amdgcn_wave_barrier();
    for (int tl=0; tl<64; ++tl) {
      const float x0 = xbuf[wave][tl*5+0], x1v = xbuf[wave][tl*5+1],
                  x2v = xbuf[wave][tl*5+2], x3v = xbuf[wave][tl*5+3],
                  x4v = xbuf[wave][tl*5+4];
      float a0a = bb0, a0b = 0.f, a1a = bb1, a1b = 0.f;
      a0a = fmaf(wi0[0],x0,a0a);  a1a = fmaf(wi1[0],x0,a1a);
      a0b = fmaf(wi0[1],x1v,a0b); a1b = fmaf(wi1[1],x1v,a1b);
      a0a = fmaf(wi0[2],x2v,a0a); a1a = fmaf(wi1[2],x2v,a1a);
      a0b = fmaf(wi0[3],x3v,a0b); a1b = fmaf(wi1[3],x3v,a1b);
      a0a = fmaf(wi0[4],x4v,a0a); a1a = fmaf(wi1[4],x4v,a1a);
      // h matvec: 16 packed pairs via 4x ds_read_b128, v_dot2_f32_f16
      const float4* hp4 = (const float4*)&hp[wave][0];
      #pragma unroll
      for (int q=0;q<4;q++){
        float4 hv = hp4[q];
        h2v h0=bch2(hv.x), h1=bch2(hv.y), hq2=bch2(hv.z), h3=bch2(hv.w);
        a0a = fdot2(wr0p[4*q+0], h0,  a0a);
        a0b = fdot2(wr0p[4*q+1], h1,  a0b);
        a1a = fdot2(wr1p[4*q+0], h0,  a1a);
        a1b = fdot2(wr1p[4*q+1], h1,  a1b);
        a0a = fdot2(wr0p[4*q+2], hq2, a0a);
        a0b = fdot2(wr0p[4*q+3], h3,  a0b);
        a1a = fdot2(wr1p[4*q+2], hq2, a1a);
        a1b = fdot2(wr1p[4*q+3], h3,  a1b);
      }
      const float ac0 = a0a + a0b;
      const float ac1 = a1a + a1b;
      const float s0 = sigmoid_fast(ac0);               // i (half0) or f (half1)
      const float ss = sigmoid_fast(sIn*ac1);
      const float go = fmaf(aMul, ss, aAdd);            // g (half0) or o (half1)
      const float o0 = __shfl_xor(s0, 32);
      const float o1 = __shfl_xor(go, 32);
      const float iv = half ? o0 : s0;
      const float fv = half ? s0 : o0;
      const float gv = half ? o1 : go;
      const float ov = half ? go : o1;
      c = fmaf(fv, c, iv*gv);
      const float hnew = ov * tanh_fast(c);
      hlast = hnew;
      const float hup = __shfl_xor(hnew, 1);            // partner for packing
      if (half==0 && act && !(j&1)) {
        h2v pk; pk.x = (_Float16)hnew; pk.y = (_Float16)hup;
        hp[wave][j>>1] = __builtin_bit_cast(float, pk);
      }
      __builtin_amdgcn_wave_barrier();
    }
  }

  // ---- tail: q = h@Wq^T+bq (pre-scaled by 1/sqrt(HD)); k,v from c ----
  float* cbuf = &xbuf[wave][0];     // c fp32, 32 slots zero-padded
  float* hb32 = &xbuf[wave][32];    // h fp32, 32 slots zero-padded
  if (half==0) { cbuf[lane] = act ? c : 0.f; hb32[lane] = act ? hlast : 0.f; }
  __builtin_amdgcn_wave_barrier();
  if (half==0 && act) ho[b*NE + j] = hlast;
  const float QS = 0.31622776601683794f;     // 1/sqrt(10)
  #pragma unroll
  for (int rep=0; rep<2; ++rep) {
    const int o = lane + rep*64;
    if (o < 90) {
      const float* wrow = in_proj_w + o*NE;
      const float* src  = (o < NE) ? hb32 : cbuf;
      float acc = in_proj_b[o];
      #pragma unroll
      for (int k2=0;k2<NE;k2++) acc = fmaf(wrow[k2], src[k2], acc);
      if (o < 30)      { qo[(o/10)*B10 + b*10 + (o%10)] = acc * QS; }
      else if (o < 60) { const int u=o-30; ko[(u/10)*B10 + b*10 + (u%10)] = acc; }
      else             { const int u=o-60; vo[(u/10)*B10 + b*10 + (u%10)] = acc; }
    }
  }
}

// ---------------------------------------------------------------------------
// Kernel 2: flash-style attention over the batch axis. grid=(64 qtiles, 3 heads),
// block=512 (8 waves). 128-key tiles staged into LDS cooperatively (float4,
// coalesced, double-buffered, 1 barrier/tile). Wave w consumes its 16-key slice
// for all 64 query rows (lane = q row) via wave-uniform LDS broadcast reads.
// Online softmax per thread; LDS merge of the 8 partials per query.
// ---------------------------------------------------------------------------
extern "C" __global__ void __launch_bounds__(512)
attn_k(const float* __restrict__ q, const float* __restrict__ k,
       const float* __restrict__ v, float* __restrict__ ctx)
{
  __shared__ __align__(16) float ktb[2][1280];
  __shared__ __align__(16) float vtb[2][1280];
  __shared__ float red[8][64][12];
  const int t    = threadIdx.x;
  const int ql   = t & 63;
  const int w    = t >> 6;
  const int head = blockIdx.y;
  const int qr   = blockIdx.x*64 + ql;
  const float* kh = k + (size_t)head*B10;
  const float* vh = v + (size_t)head*B10;
  float qreg[10];
  {
    const float2* qp = (const float2*)(q + (size_t)head*B10 + qr*10);
    #pragma unroll
    for (int i=0;i<5;i++){ float2 t2=qp[i]; qreg[2*i]=t2.x; qreg[2*i+1]=t2.y; }
  }
  float m = -INFINITY, l = 0.f, acc[10];
  #pragma unroll
  for (int d=0;d<10;d++) acc[d]=0.f;

  // prologue: stage tile 0 into buffer 0
  {
    const float4* ks4 = (const float4*)kh;
    const float4* vs4 = (const float4*)vh;
    for (int i=t; i<640; i+=512){
      if (i < 320) ((float4*)&ktb[0][0])[i]     = ks4[i];
      else         ((float4*)&vtb[0][0])[i-320] = vs4[i-320];
    }
  }
  for (int ti=0; ti<32; ++ti){
    __syncthreads();   // staging of tile ti complete; reads of buf (ti+1)&1 done
    const int cur = ti & 1;
    if (ti+1 < 32){
      const int nxt = cur ^ 1;
      const float4* ks4 = (const float4*)(kh + (size_t)(ti+1)*1280);
      const float4* vs4 = (const float4*)(vh + (size_t)(ti+1)*1280);
      for (int i=t; i<640; i+=512){
        if (i < 320) ((float4*)&ktb[nxt][0])[i]     = ks4[i];
        else         ((float4*)&vtb[nxt][0])[i-320] = vs4[i-320];
      }
    }
    // this wave's 16 keys of the 128-tile
    const float* kb = &ktb[cur][w*160];
    const float* vb = &vtb[cur][w*160];
    float s[16];
    #pragma unroll
    for (int u=0;u<16;u++){
      const float2* kp = (const float2*)(kb + u*10);
      float sv = 0.f;
      #pragma unroll
      for (int i=0;i<5;i++){ float2 kk=kp[i]; sv=fmaf(qreg[2*i],kk.x,sv); sv=fmaf(qreg[2*i+1],kk.y,sv); }
      s[u]=sv;
    }
    float mc = s[0];
    #pragma unroll
    for (int u=1;u<16;u++) mc = fmaxf(mc, s[u]);
    const float mnew = fmaxf(m, mc);
    const float corr = fexp2(L2E*(m - mnew));   // m=-inf first tile -> 0
    l *= corr;
    #pragma unroll
    for (int d=0;d<10;d++) acc[d]*=corr;
    #pragma unroll
    for (int u=0;u<16;u++){
      const float p = fexp2(L2E*(s[u]-mnew));
      l += p;
      const float2* vp = (const float2*)(vb + u*10);
      #pragma unroll
      for (int i=0;i<5;i++){ float2 vv=vp[i]; acc[2*i]=fmaf(p,vv.x,acc[2*i]); acc[2*i+1]=fmaf(p,vv.y,acc[2*i+1]); }
    }
    m = mnew;
  }
  red[w][ql][0]=m; red[w][ql][1]=l;
  #pragma unroll
  for (int d=0;d<10;d++) red[w][ql][2+d]=acc[d];
  __syncthreads();
  if (t < 64) {
    float M = red[0][t][0];
    #pragma unroll
    for (int i=1;i<8;i++) M = fmaxf(M, red[i][t][0]);
    float L=0.f, o[10];
    #pragma unroll
    for (int d=0;d<10;d++) o[d]=0.f;
    #pragma unroll
    for (int i=0;i<8;i++){
      const float wgt = fexp2(L2E*(red[i][t][0]-M));
      L = fmaf(red[i][t][1], wgt, L);
      #pragma unroll
      for (int d=0;d<10;d++) o[d]=fmaf(red[i][t][2+d],wgt,o[d]);
    }
    const float invL = 1.f/L;
    float* cp = ctx + (size_t)head*B10 + (size_t)(blockIdx.x*64 + t)*10;
    #pragma unroll
    for (int d=0;d<10;d++) cp[d]=o[d]*invL;
  }
}

// ---------------------------------------------------------------------------
// Kernel 3: out_proj + residual + LN + MLP(exact GELU) + LN + head.
// One wave per row; row vector staged in a per-wave 32-float LDS buffer.
// ---------------------------------------------------------------------------
extern "C" __global__ void __launch_bounds__(256)
tail_k(const float* __restrict__ ctx, const float* __restrict__ hn,
       const float* __restrict__ out_proj_w, const float* __restrict__ out_proj_b,
       const float* __restrict__ fc1_w, const float* __restrict__ fc1_b,
       const float* __restrict__ fc2_w, const float* __restrict__ fc2_b,
       const float* __restrict__ ln_g, const float* __restrict__ ln_b,
       const float* __restrict__ out_w, const float* __restrict__ out_b,
       float* __restrict__ out)
{
  __shared__ __align__(16) float buf[4][32];
  const int wave = threadIdx.x >> 6;
  const int lane = threadIdx.x & 63;
  const int b = blockIdx.x*4 + wave;
  const bool act = (lane < NE);
  if (lane < 32) buf[wave][lane] = 0.f;
  __builtin_amdgcn_wave_barrier();
  if (act) buf[wave][lane] = ctx[(lane/10)*B10 + b*10 + (lane%10)];
  __builtin_amdgcn_wave_barrier();
  float arr[32];
  loadarr32(arr, &buf[wave][0]);
  const float hv = act ? hn[b*NE+lane] : 0.f;
  float x = 0.f;
  if (act) {
    float a = out_proj_b[lane];
    #pragma unroll
    for (int k2=0;k2<NE;k2++) a = fmaf(out_proj_w[lane*NE+k2], arr[k2], a);
    x = a + hv;                       // attn_out + h_n
  }
  // LN1
  __builtin_amdgcn_wave_barrier();
  if (act) buf[wave][lane] = x;
  __builtin_amdgcn_wave_barrier();
  loadarr32(arr, &buf[wave][0]);
  float s1=0.f, s2=0.f;
  #pragma unroll
  for (int k2=0;k2<32;k2++){ s1+=arr[k2]; s2=fmaf(arr[k2],arr[k2],s2); }
  float mu = s1*(1.f/30.f);
  float var = s2*(1.f/30.f) - mu*mu;
  float rs = rsqrtf(var + 1e-5f);
  float x1 = 0.f;
  if (act) x1 = fmaf((x-mu)*rs, ln_g[lane], ln_b[lane]);
  // fc1 + exact GELU
  __builtin_amdgcn_wave_barrier();
  if (act) buf[wave][lane] = x1;
  __builtin_amdgcn_wave_barrier();
  loadarr32(arr, &buf[wave][0]);
  float gv = 0.f;
  if (act) {
    float a = fc1_b[lane];
    #pragma unroll
    for (int k2=0;k2<NE;k2++) a = fmaf(fc1_w[lane*NE+k2], arr[k2], a);
    gv = 0.5f*a*(1.f + erff(a*0.70710678118654752f));
  }
  // fc2
  __builtin_amdgcn_wave_barrier();
  if (act) buf[wave][lane] = gv;
  __builtin_amdgcn_wave_barrier();
  loadarr32(arr, &buf[wave][0]);
  float y = 0.f;
  if (act) {
    float a = fc2_b[lane];
    #pragma unroll
    for (int k2=0;k2<NE;k2++) a = fmaf(fc2_w[lane*NE+k2], arr[k2], a);
    y = x1 + a;                        // residual x1 + fc
  }
  // LN2
  __builtin_amdgcn_wave_barrier();
  if (act) buf[wave][lane] = y;
  __builtin_amdgcn_wave_barrier();
  loadarr32(arr, &buf[wave][0]);
  s1=0.f; s2=0.f;
  #pragma unroll
  for (int k2=0;k2<32;k2++){ s1+=arr[k2]; s2=fmaf(arr[k2],arr[k2],s2); }
  mu = s1*(1.f/30.f);
  var = s2*(1.f/30.f) - mu*mu;
  rs = rsqrtf(var + 1e-5f);
  float x2 = 0.f;
  if (act) x2 = fmaf((y-mu)*rs, ln_g[lane], ln_b[lane]);
  // head: [3,30]
  __builtin_amdgcn_wave_barrier();
  if (act) buf[wave][lane] = x2;
  __builtin_amdgcn_wave_barrier();
  loadarr32(arr, &buf[wave][0]);
  if (lane < 3) {
    float a = out_b[lane];
    #pragma unroll
    for (int k2=0;k2<NE;k2++) a = fmaf(out_w[lane*NE+k2], arr[k2], a);
    out[b*3 + lane] = a;
  }
}

extern "C" void kernel_launch(void* const* d_in, const int* in_sizes, int n_in,
                              void* d_out, int out_size, void* d_ws, size_t ws_size,
                              hipStream_t stream)
{
  const float* input      = (const float*)d_in[0];
  const float* w_ih       = (const float*)d_in[1];
  const float* w_hh       = (const float*)d_in[2];
  const float* b_ih       = (const float*)d_in[3];
  const float* b_hh       = (const float*)d_in[4];
  const float* in_proj_w  = (const float*)d_in[5];
  const float* in_proj_b  = (const float*)d_in[6];
  const float* out_proj_w = (const float*)d_in[7];
  const float* out_proj_b = (const float*)d_in[8];
  const float* fc1_w      = (const float*)d_in[9];
  const float* fc1_b      = (const float*)d_in[10];
  const float* fc2_w      = (const float*)d_in[11];
  const float* fc2_b      = (const float*)d_in[12];
  const float* ln_g       = (const float*)d_in[13];
  const float* ln_b       = (const float*)d_in[14];
  const float* out_w      = (const float*)d_in[15];
  const float* out_b      = (const float*)d_in[16];

  float* ws = (float*)d_ws;
  float* qo = ws;                 // [3][4096][10]
  float* ko = ws + 122880;        // [3][4096][10]
  float* vo = ws + 245760;        // [3][4096][10]
  float* hn = ws + 368640;        // [4096][30]
  float* cx = ws + 491520;        // [3][4096][10]

  lstm_k<<<Bsz/4, 256, 0, stream>>>(input, w_ih, w_hh, b_ih, b_hh,
                                    in_proj_w, in_proj_b, qo, ko, vo, hn);
  attn_k<<<dim3(Bsz/64, 3), 512, 0, stream>>>(qo, ko, vo, cx);
  tail_k<<<Bsz/4, 256, 0, stream>>>(cx, hn, out_proj_w, out_proj_b,
                                    fc1_w, fc1_b, fc2_w, fc2_b,
                                    ln_g, ln_b, out_w, out_b, (float*)d_out);
}

// Round 3
// 494.962 us; speedup vs baseline: 1.2125x; 1.0476x over previous
//
#include <hip/hip_runtime.h>
#include <math.h>

// Problem constants
#define Bsz  4096
#define Tlen 512
#define NE   30
#define NIN  5
#define HD10 10
#define B10  (Bsz*HD10)   // per-head plane: 40960 floats

typedef _Float16 h2v __attribute__((ext_vector_type(2)));

__device__ __forceinline__ float fexp2(float x){ return __builtin_amdgcn_exp2f(x); }
__device__ __forceinline__ float frcp (float x){ return __builtin_amdgcn_rcpf(x); }
#define L2E 1.4426950408889634f
__device__ __forceinline__ float sigmoid_fast(float x){ return frcp(1.f + fexp2(-L2E*x)); }
__device__ __forceinline__ float tanh_fast(float x){ return 1.f - 2.f*frcp(1.f + fexp2((2.f*L2E)*x)); }

#if __has_builtin(__builtin_amdgcn_fdot2)
__device__ __forceinline__ float fdot2(h2v a, h2v b, float c){
  return __builtin_amdgcn_fdot2(a, b, c, false);
}
#else
__device__ __forceinline__ float fdot2(h2v a, h2v b, float c){
  return fmaf((float)a.x, (float)b.x, fmaf((float)a.y, (float)b.y, c));
}
#endif

__device__ __forceinline__ h2v bch2(float x){ return __builtin_bit_cast(h2v, x); }

__device__ __forceinline__ void loadarr32(float arr[32], const float* bufrow){
  const float4* p4 = (const float4*)bufrow;
  #pragma unroll
  for (int q4=0;q4<8;q4++){ float4 vv=p4[q4]; arr[4*q4]=vv.x; arr[4*q4+1]=vv.y; arr[4*q4+2]=vv.z; arr[4*q4+3]=vv.w; }
}

// ---------------------------------------------------------------------------
// Kernel 1: fused x-proj + LSTM recurrence + qkv projection.
// One wave per batch element. Lanes: half=lane>>5, j=lane&31.
//   half0,j<30: gates i[j] (acc0) and g[j] (acc1)
//   half1,j<30: gates f[j] (acc0) and o[j] (acc1)
// h state packed fp16 (half2 pairs) in LDS; recurrence matvec via v_dot2_f32_f16
// (fp32 accumulate). Input projection stays fp32. Wave-synchronous.
// waves_per_eu(4,4): grid is exactly 4 blocks/CU -> 4 waves/EU; pinning max=4
// gives the allocator the full 128-VGPR budget so weights stay in arch VGPRs
// (R2's VGPR_Count=40 proved they were demoted to AGPRs -> accvgpr_read per use).
// ---------------------------------------------------------------------------
extern "C" __global__ void __launch_bounds__(256)
__attribute__((amdgpu_waves_per_eu(4,4)))
lstm_k(const float* __restrict__ input, const float* __restrict__ w_ih,
       const float* __restrict__ w_hh, const float* __restrict__ b_ih,
       const float* __restrict__ b_hh, const float* __restrict__ in_proj_w,
       const float* __restrict__ in_proj_b,
       float* __restrict__ qo, float* __restrict__ ko, float* __restrict__ vo,
       float* __restrict__ ho)
{
  __shared__ __align__(16) float xbuf[4][320];  // 64-step input chunk per wave
  __shared__ __align__(16) float hp[4][16];     // h as 16 packed half2 (pair 15 = 0)
  const int wave = threadIdx.x >> 6;
  const int lane = threadIdx.x & 63;
  const int half = lane >> 5;
  const int j    = lane & 31;
  const int b    = blockIdx.x * 4 + wave;
  const bool act = (j < NE);
  const int g0 = half*NE + j;        // i- or f-row
  const int g1 = 60 + half*NE + j;   // g- or o-row

  // packed fp16 weight pairs (index 15 = zero pad)
  h2v wr0p[16], wr1p[16];
  float wi0[NIN], wi1[NIN];
  float bb0 = 0.f, bb1 = 0.f;
  #pragma unroll
  for (int k2=0;k2<16;k2++){ wr0p[k2]=(h2v)0; wr1p[k2]=(h2v)0; }
  #pragma unroll
  for (int m=0;m<NIN;m++){ wi0[m]=0.f; wi1[m]=0.f; }
  if (act) {
    #pragma unroll
    for (int k2=0;k2<15;k2++){
      h2v w0, w1;
      w0.x = (_Float16)w_hh[g0*NE+2*k2];   w0.y = (_Float16)w_hh[g0*NE+2*k2+1];
      w1.x = (_Float16)w_hh[g1*NE+2*k2];   w1.y = (_Float16)w_hh[g1*NE+2*k2+1];
      wr0p[k2]=w0; wr1p[k2]=w1;
    }
    #pragma unroll
    for (int m=0;m<NIN;m++){ wi0[m]=w_ih[g0*NIN+m]; wi1[m]=w_ih[g1*NIN+m]; }
    bb0 = b_ih[g0]+b_hh[g0];
    bb1 = b_ih[g1]+b_hh[g1];
  }
  if (lane < 16) hp[wave][lane] = 0.f;   // zero-packed h (incl pad pair 15)
  float c = 0.f, hlast = 0.f;
  // half0 -> tanh via 2*sigmoid(2x)-1 ; half1 -> sigmoid(x)
  const float sIn  = half ? 1.f : 2.f;
  const float aMul = half ? 1.f : 2.f;
  const float aAdd = half ? 0.f : -1.f;
  const float* xrow = input + (size_t)b * (Tlen*NIN);
  __builtin_amdgcn_wave_barrier();

  for (int tc = 0; tc < Tlen; tc += 64) {
    // stage 64 steps of input (320 floats) into LDS, coalesced
    #pragma unroll
    for (int r=0;r<5;r++) xbuf[wave][lane + 64*r] = xrow[tc*5 + lane + 64*r];
    __builtin_amdgcn_wave_barrier();
    for (int tl=0; tl<64; ++tl) {
      const float x0 = xbuf[wave][tl*5+0], x1v = xbuf[wave][tl*5+1],
                  x2v = xbuf[wave][tl*5+2], x3v = xbuf[wave][tl*5+3],
                  x4v = xbuf[wave][tl*5+4];
      float a0a = bb0, a0b = 0.f, a1a = bb1, a1b = 0.f;
      a0a = fmaf(wi0[0],x0,a0a);  a1a = fmaf(wi1[0],x0,a1a);
      a0b = fmaf(wi0[1],x1v,a0b); a1b = fmaf(wi1[1],x1v,a1b);
      a0a = fmaf(wi0[2],x2v,a0a); a1a = fmaf(wi1[2],x2v,a1a);
      a0b = fmaf(wi0[3],x3v,a0b); a1b = fmaf(wi1[3],x3v,a1b);
      a0a = fmaf(wi0[4],x4v,a0a); a1a = fmaf(wi1[4],x4v,a1a);
      // h matvec: 16 packed pairs via 4x ds_read_b128, v_dot2_f32_f16
      const float4* hp4 = (const float4*)&hp[wave][0];
      #pragma unroll
      for (int q=0;q<4;q++){
        float4 hv = hp4[q];
        h2v h0=bch2(hv.x), h1=bch2(hv.y), hq2=bch2(hv.z), h3=bch2(hv.w);
        a0a = fdot2(wr0p[4*q+0], h0,  a0a);
        a0b = fdot2(wr0p[4*q+1], h1,  a0b);
        a1a = fdot2(wr1p[4*q+0], h0,  a1a);
        a1b = fdot2(wr1p[4*q+1], h1,  a1b);
        a0a = fdot2(wr0p[4*q+2], hq2, a0a);
        a0b = fdot2(wr0p[4*q+3], h3,  a0b);
        a1a = fdot2(wr1p[4*q+2], hq2, a1a);
        a1b = fdot2(wr1p[4*q+3], h3,  a1b);
      }
      const float ac0 = a0a + a0b;
      const float ac1 = a1a + a1b;
      const float s0 = sigmoid_fast(ac0);               // i (half0) or f (half1)
      const float ss = sigmoid_fast(sIn*ac1);
      const float go = fmaf(aMul, ss, aAdd);            // g (half0) or o (half1)
      const float o0 = __shfl_xor(s0, 32);
      const float o1 = __shfl_xor(go, 32);
      const float iv = half ? o0 : s0;
      const float fv = half ? s0 : o0;
      const float gv = half ? o1 : go;
      const float ov = half ? go : o1;
      c = fmaf(fv, c, iv*gv);
      const float hnew = ov * tanh_fast(c);
      hlast = hnew;
      const float hup = __shfl_xor(hnew, 1);            // partner for packing
      if (half==0 && act && !(j&1)) {
        h2v pk; pk.x = (_Float16)hnew; pk.y = (_Float16)hup;
        hp[wave][j>>1] = __builtin_bit_cast(float, pk);
      }
      __builtin_amdgcn_wave_barrier();
    }
  }

  // ---- tail: q = h@Wq^T+bq (pre-scaled by 1/sqrt(HD)); k,v from c ----
  float* cbuf = &xbuf[wave][0];     // c fp32, 32 slots zero-padded
  float* hb32 = &xbuf[wave][32];    // h fp32, 32 slots zero-padded
  if (half==0) { cbuf[lane] = act ? c : 0.f; hb32[lane] = act ? hlast : 0.f; }
  __builtin_amdgcn_wave_barrier();
  if (half==0 && act) ho[b*NE + j] = hlast;
  const float QS = 0.31622776601683794f;     // 1/sqrt(10)
  #pragma unroll
  for (int rep=0; rep<2; ++rep) {
    const int o = lane + rep*64;
    if (o < 90) {
      const float* wrow = in_proj_w + o*NE;
      const float* src  = (o < NE) ? hb32 : cbuf;
      float acc = in_proj_b[o];
      #pragma unroll
      for (int k2=0;k2<NE;k2++) acc = fmaf(wrow[k2], src[k2], acc);
      if (o < 30)      { qo[(o/10)*B10 + b*10 + (o%10)] = acc * QS; }
      else if (o < 60) { const int u=o-30; ko[(u/10)*B10 + b*10 + (u%10)] = acc; }
      else             { const int u=o-60; vo[(u/10)*B10 + b*10 + (u%10)] = acc; }
    }
  }
}

// ---------------------------------------------------------------------------
// Kernel 2: flash-style attention over the batch axis. grid=(64 qtiles, 3 heads),
// block=512 (8 waves). 128-key tiles staged into LDS cooperatively (float4,
// coalesced, double-buffered, 1 barrier/tile). Wave w consumes its 16-key slice
// for all 64 query rows (lane = q row) via wave-uniform LDS broadcast reads.
// Online softmax per thread; LDS merge of the 8 partials per query.
// waves_per_eu(2,2): 1 block/CU = 2 waves/EU -> 256-VGPR budget; the live set
// (s[16]+acc[10]+qreg[10]+staging) must stay in VGPRs, never scratch.
// ---------------------------------------------------------------------------
extern "C" __global__ void __launch_bounds__(512)
__attribute__((amdgpu_waves_per_eu(2,2)))
attn_k(const float* __restrict__ q, const float* __restrict__ k,
       const float* __restrict__ v, float* __restrict__ ctx)
{
  __shared__ __align__(16) float ktb[2][1280];
  __shared__ __align__(16) float vtb[2][1280];
  __shared__ float red[8][64][12];
  const int t    = threadIdx.x;
  const int ql   = t & 63;
  const int w    = t >> 6;
  const int head = blockIdx.y;
  const int qr   = blockIdx.x*64 + ql;
  const float* kh = k + (size_t)head*B10;
  const float* vh = v + (size_t)head*B10;
  float qreg[10];
  {
    const float2* qp = (const float2*)(q + (size_t)head*B10 + qr*10);
    #pragma unroll
    for (int i=0;i<5;i++){ float2 t2=qp[i]; qreg[2*i]=t2.x; qreg[2*i+1]=t2.y; }
  }
  float m = -INFINITY, l = 0.f, acc[10];
  #pragma unroll
  for (int d=0;d<10;d++) acc[d]=0.f;

  // prologue: stage tile 0 into buffer 0
  {
    const float4* ks4 = (const float4*)kh;
    const float4* vs4 = (const float4*)vh;
    for (int i=t; i<640; i+=512){
      if (i < 320) ((float4*)&ktb[0][0])[i]     = ks4[i];
      else         ((float4*)&vtb[0][0])[i-320] = vs4[i-320];
    }
  }
  for (int ti=0; ti<32; ++ti){
    __syncthreads();   // staging of tile ti complete; reads of buf (ti+1)&1 done
    const int cur = ti & 1;
    if (ti+1 < 32){
      const int nxt = cur ^ 1;
      const float4* ks4 = (const float4*)(kh + (size_t)(ti+1)*1280);
      const float4* vs4 = (const float4*)(vh + (size_t)(ti+1)*1280);
      for (int i=t; i<640; i+=512){
        if (i < 320) ((float4*)&ktb[nxt][0])[i]     = ks4[i];
        else         ((float4*)&vtb[nxt][0])[i-320] = vs4[i-320];
      }
    }
    // this wave's 16 keys of the 128-tile
    const float* kb = &ktb[cur][w*160];
    const float* vb = &vtb[cur][w*160];
    float s[16];
    #pragma unroll
    for (int u=0;u<16;u++){
      const float2* kp = (const float2*)(kb + u*10);
      float sv = 0.f;
      #pragma unroll
      for (int i=0;i<5;i++){ float2 kk=kp[i]; sv=fmaf(qreg[2*i],kk.x,sv); sv=fmaf(qreg[2*i+1],kk.y,sv); }
      s[u]=sv;
    }
    float mc = s[0];
    #pragma unroll
    for (int u=1;u<16;u++) mc = fmaxf(mc, s[u]);
    const float mnew = fmaxf(m, mc);
    const float corr = fexp2(L2E*(m - mnew));   // m=-inf first tile -> 0
    l *= corr;
    #pragma unroll
    for (int d=0;d<10;d++) acc[d]*=corr;
    #pragma unroll
    for (int u=0;u<16;u++){
      const float p = fexp2(L2E*(s[u]-mnew));
      l += p;
      const float2* vp = (const float2*)(vb + u*10);
      #pragma unroll
      for (int i=0;i<5;i++){ float2 vv=vp[i]; acc[2*i]=fmaf(p,vv.x,acc[2*i]); acc[2*i+1]=fmaf(p,vv.y,acc[2*i+1]); }
    }
    m = mnew;
  }
  red[w][ql][0]=m; red[w][ql][1]=l;
  #pragma unroll
  for (int d=0;d<10;d++) red[w][ql][2+d]=acc[d];
  __syncthreads();
  if (t < 64) {
    float M = red[0][t][0];
    #pragma unroll
    for (int i=1;i<8;i++) M = fmaxf(M, red[i][t][0]);
    float L=0.f, o[10];
    #pragma unroll
    for (int d=0;d<10;d++) o[d]=0.f;
    #pragma unroll
    for (int i=0;i<8;i++){
      const float wgt = fexp2(L2E*(red[i][t][0]-M));
      L = fmaf(red[i][t][1], wgt, L);
      #pragma unroll
      for (int d=0;d<10;d++) o[d]=fmaf(red[i][t][2+d],wgt,o[d]);
    }
    const float invL = 1.f/L;
    float* cp = ctx + (size_t)head*B10 + (size_t)(blockIdx.x*64 + t)*10;
    #pragma unroll
    for (int d=0;d<10;d++) cp[d]=o[d]*invL;
  }
}

// ---------------------------------------------------------------------------
// Kernel 3: out_proj + residual + LN + MLP(exact GELU) + LN + head.
// One wave per row; row vector staged in a per-wave 32-float LDS buffer.
// ---------------------------------------------------------------------------
extern "C" __global__ void __launch_bounds__(256)
tail_k(const float* __restrict__ ctx, const float* __restrict__ hn,
       const float* __restrict__ out_proj_w, const float* __restrict__ out_proj_b,
       const float* __restrict__ fc1_w, const float* __restrict__ fc1_b,
       const float* __restrict__ fc2_w, const float* __restrict__ fc2_b,
       const float* __restrict__ ln_g, const float* __restrict__ ln_b,
       const float* __restrict__ out_w, const float* __restrict__ out_b,
       float* __restrict__ out)
{
  __shared__ __align__(16) float buf[4][32];
  const int wave = threadIdx.x >> 6;
  const int lane = threadIdx.x & 63;
  const int b = blockIdx.x*4 + wave;
  const bool act = (lane < NE);
  if (lane < 32) buf[wave][lane] = 0.f;
  __builtin_amdgcn_wave_barrier();
  if (act) buf[wave][lane] = ctx[(lane/10)*B10 + b*10 + (lane%10)];
  __builtin_amdgcn_wave_barrier();
  float arr[32];
  loadarr32(arr, &buf[wave][0]);
  const float hv = act ? hn[b*NE+lane] : 0.f;
  float x = 0.f;
  if (act) {
    float a = out_proj_b[lane];
    #pragma unroll
    for (int k2=0;k2<NE;k2++) a = fmaf(out_proj_w[lane*NE+k2], arr[k2], a);
    x = a + hv;                       // attn_out + h_n
  }
  // LN1
  __builtin_amdgcn_wave_barrier();
  if (act) buf[wave][lane] = x;
  __builtin_amdgcn_wave_barrier();
  loadarr32(arr, &buf[wave][0]);
  float s1=0.f, s2=0.f;
  #pragma unroll
  for (int k2=0;k2<32;k2++){ s1+=arr[k2]; s2=fmaf(arr[k2],arr[k2],s2); }
  float mu = s1*(1.f/30.f);
  float var = s2*(1.f/30.f) - mu*mu;
  float rs = rsqrtf(var + 1e-5f);
  float x1 = 0.f;
  if (act) x1 = fmaf((x-mu)*rs, ln_g[lane], ln_b[lane]);
  // fc1 + exact GELU
  __builtin_amdgcn_wave_barrier();
  if (act) buf[wave][lane] = x1;
  __builtin_amdgcn_wave_barrier();
  loadarr32(arr, &buf[wave][0]);
  float gv = 0.f;
  if (act) {
    float a = fc1_b[lane];
    #pragma unroll
    for (int k2=0;k2<NE;k2++) a = fmaf(fc1_w[lane*NE+k2], arr[k2], a);
    gv = 0.5f*a*(1.f + erff(a*0.70710678118654752f));
  }
  // fc2
  __builtin_amdgcn_wave_barrier();
  if (act) buf[wave][lane] = gv;
  __builtin_amdgcn_wave_barrier();
  loadarr32(arr, &buf[wave][0]);
  float y = 0.f;
  if (act) {
    float a = fc2_b[lane];
    #pragma unroll
    for (int k2=0;k2<NE;k2++) a = fmaf(fc2_w[lane*NE+k2], arr[k2], a);
    y = x1 + a;                        // residual x1 + fc
  }
  // LN2
  __builtin_amdgcn_wave_barrier();
  if (act) buf[wave][lane] = y;
  __builtin_amdgcn_wave_barrier();
  loadarr32(arr, &buf[wave][0]);
  s1=0.f; s2=0.f;
  #pragma unroll
  for (int k2=0;k2<32;k2++){ s1+=arr[k2]; s2=fmaf(arr[k2],arr[k2],s2); }
  mu = s1*(1.f/30.f);
  var = s2*(1.f/30.f) - mu*mu;
  rs = rsqrtf(var + 1e-5f);
  float x2 = 0.f;
  if (act) x2 = fmaf((y-mu)*rs, ln_g[lane], ln_b[lane]);
  // head: [3,30]
  __builtin_amdgcn_wave_barrier();
  if (act) buf[wave][lane] = x2;
  __builtin_amdgcn_wave_barrier();
  loadarr32(arr, &buf[wave][0]);
  if (lane < 3) {
    float a = out_b[lane];
    #pragma unroll
    for (int k2=0;k2<NE;k2++) a = fmaf(out_w[lane*NE+k2], arr[k2], a);
    out[b*3 + lane] = a;
  }
}

extern "C" void kernel_launch(void* const* d_in, const int* in_sizes, int n_in,
                              void* d_out, int out_size, void* d_ws, size_t ws_size,
                              hipStream_t stream)
{
  const float* input      = (const float*)d_in[0];
  const float* w_ih       = (const float*)d_in[1];
  const float* w_hh       = (const float*)d_in[2];
  const float* b_ih       = (const float*)d_in[3];
  const float* b_hh       = (const float*)d_in[4];
  const float* in_proj_w  = (const float*)d_in[5];
  const float* in_proj_b  = (const float*)d_in[6];
  const float* out_proj_w = (const float*)d_in[7];
  const float* out_proj_b = (const float*)d_in[8];
  const float* fc1_w      = (const float*)d_in[9];
  const float* fc1_b      = (const float*)d_in[10];
  const float* fc2_w      = (const float*)d_in[11];
  const float* fc2_b      = (const float*)d_in[12];
  const float* ln_g       = (const float*)d_in[13];
  const float* ln_b       = (const float*)d_in[14];
  const float* out_w      = (const float*)d_in[15];
  const float* out_b      = (const float*)d_in[16];

  float* ws = (float*)d_ws;
  float* qo = ws;                 // [3][4096][10]
  float* ko = ws + 122880;        // [3][4096][10]
  float* vo = ws + 245760;        // [3][4096][10]
  float* hn = ws + 368640;        // [4096][30]
  float* cx = ws + 491520;        // [3][4096][10]

  lstm_k<<<Bsz/4, 256, 0, stream>>>(input, w_ih, w_hh, b_ih, b_hh,
                                    in_proj_w, in_proj_b, qo, ko, vo, hn);
  attn_k<<<dim3(Bsz/64, 3), 512, 0, stream>>>(qo, ko, vo, cx);
  tail_k<<<Bsz/4, 256, 0, stream>>>(cx, hn, out_proj_w, out_proj_b,
                                    fc1_w, fc1_b, fc2_w, fc2_b,
                                    ln_g, ln_b, out_w, out_b, (float*)d_out);
}